// Round 2
// baseline (3281.648 us; speedup 1.0000x reference)
//
#include <hip/hip_runtime.h>

#ifndef __has_builtin
#define __has_builtin(x) 0
#endif

#define DEV static __device__ __forceinline__

// problem dims
#define TT 128
#define BB 256
#define HH 128
#define KK 64
#define VV 128
#define OO 512
#define JBLK 132                // 128 hypernet j-blocks + 4 blocks for hyp_b2 (bias @ h)
#define KEXT (JBLK*32)          // 4224

static const size_t PRED_OFF  = 0;
static const size_t LOGIT_OFF = (size_t)TT*BB*OO;                  // 16777216
static const size_t INFH_OFF  = LOGIT_OFF + (size_t)TT*BB*OO;      // 33554432
static const size_t GEN_OFF   = INFH_OFF + (size_t)TT*BB*HH;       // 37748736
static const size_t GATE_OFF  = GEN_OFF + (size_t)TT*BB*HH;        // 41943040

typedef float f32x4 __attribute__((ext_vector_type(4)));

DEV unsigned short f2bf(float x){
  unsigned int u = __float_as_uint(x);
  u = (u + 0x7fffu + ((u >> 16) & 1u)) >> 16;   // RNE
  return (unsigned short)u;
}
DEV float bf2f(unsigned short v){ return __uint_as_float(((unsigned int)v) << 16); }

// ---------------- fp8 e4m3 helpers ----------------------------------------------------
DEV unsigned char enc8_sw(float x){
  unsigned int u = __float_as_uint(x);
  unsigned int s = (u >> 24) & 0x80u;
  int e = (int)((u >> 23) & 0xffu) - 127;
  unsigned int m = u & 0x7fffffu;
  if (((u >> 23) & 0xffu) == 0) return (unsigned char)s;
  if (e < -10) return (unsigned char)s;
  if (e >= -6) {
    unsigned int mant = m >> 20, rem = m & 0xfffffu;
    if (rem > 0x80000u || (rem == 0x80000u && (mant & 1u))) mant++;
    unsigned int ee = (unsigned int)(e + 7);
    if (mant == 8u) { mant = 0u; ee++; }
    if (ee >= 15u) return (unsigned char)(s | 0x7Eu);
    return (unsigned char)(s | (ee << 3) | mant);
  }
  unsigned int full = 0x800000u | m;
  int sh = 20 + (-6 - e);
  unsigned int mant = full >> sh;
  unsigned int rem  = full & ((1u << sh) - 1u);
  unsigned int halfv = 1u << (sh - 1);
  if (rem > halfv || (rem == halfv && (mant & 1u))) mant++;
  if (mant >= 8u) return (unsigned char)(s | (1u << 3));
  return (unsigned char)(s | mant);
}

DEV unsigned char enc8(float v){
#if __has_builtin(__builtin_amdgcn_cvt_pk_fp8_f32)
  int r = __builtin_amdgcn_cvt_pk_fp8_f32(v, v, 0, false);
  return (unsigned char)(r & 0xff);
#else
  return enc8_sw(v);
#endif
}

DEV unsigned int pack4_fp8(float a, float b, float c, float d){
#if __has_builtin(__builtin_amdgcn_cvt_pk_fp8_f32)
  int w = __builtin_amdgcn_cvt_pk_fp8_f32(a, b, 0, false);
  w = __builtin_amdgcn_cvt_pk_fp8_f32(c, d, w, true);
  return (unsigned int)w;
#else
  return (unsigned int)enc8_sw(a) | ((unsigned int)enc8_sw(b)<<8)
       | ((unsigned int)enc8_sw(c)<<16) | ((unsigned int)enc8_sw(d)<<24);
#endif
}

// ---------------- K0: pack W2ext and gate_W to fp8 MFMA-fragment layout ----------------
// W2ext byte (j, w, l, c) at ((j*8+w)*64+l)*8 + c:
//   i = w*16 + (l&15);  k = j*32 + (l>>4)*8 + c  (A-fragment order of 16x16x32 fp8 MFMA)
//   j<128: value = hyp_W2[i*128+j][k%32] * 1024 ;  j>=128: value = hyp_b2[i*128 + (j-128)*32 + k%32] * 1024
// gate_W byte (kc, w, l, c) at ((kc*8+w)*64+l)*8 + c:
//   i = w*16 + (l&15);  k = kc*32 + (l>>4)*8 + c ; value = gW[i*256+k] * 64
#define W2_DWORDS 135168
#define GW_DWORDS 8192
__global__ __launch_bounds__(256) void k_pack(const float* __restrict__ hW2,
                                              const float* __restrict__ hb2,
                                              const float* __restrict__ gW,
                                              unsigned char* __restrict__ w2p,
                                              unsigned char* __restrict__ gwp){
  int D = blockIdx.x * 256 + threadIdx.x;
  if (D < W2_DWORDS) {
    int flat = D * 4;
    int l  = (flat >> 3) & 63;
    int w  = (flat >> 9) & 7;
    int j  = flat >> 12;
    int cb = flat & 7;              // 0 or 4
    int i  = w*16 + (l & 15);
    int db = ((l >> 4) << 3) + cb;
    unsigned int outw = 0;
    for (int cc = 0; cc < 4; ++cc) {
      int d = db + cc;              // 0..31
      float v;
      if (j < 128) v = hW2[((size_t)i*128 + j)*32 + d];
      else         v = hb2[(size_t)i*128 + (j-128)*32 + d];
      outw |= ((unsigned int)enc8(v * 1024.0f)) << (8*cc);
    }
    ((unsigned int*)w2p)[D] = outw;
  } else if (D < W2_DWORDS + GW_DWORDS) {
    int Dg = D - W2_DWORDS;
    int flat = Dg * 4;
    int l  = (flat >> 3) & 63;
    int w  = (flat >> 9) & 7;
    int kc = flat >> 12;
    int cb = flat & 7;
    int i  = w*16 + (l & 15);
    int k0 = kc*32 + ((l >> 4) << 3) + cb;
    unsigned int outw = 0;
    for (int cc = 0; cc < 4; ++cc)
      outw |= ((unsigned int)enc8(gW[(size_t)i*256 + k0 + cc] * 64.0f)) << (8*cc);
    ((unsigned int*)gwp)[Dg] = outw;
  }
}

// ---------------- K1: sequential scan, MFMA version (16 blocks x 16 samples) -----------
struct Scan2Smem {
  unsigned long long U[JBLK*64];    // 67584 B — B-fragments (fp8 x32); aliased for gate X
  unsigned long long GW[4096];      // 32768 B — gate_W fp8 fragments, resident
  float h[128*17];                  // stride-17 padded [i][g]
  float pi[128*17];
  float i2h[128*17];                // raw i2h; overwritten with gate in phase 5
  float hyps[16*32];
  float velg[64];                   // [g][c] pad 4
  float velWs[384];
  float velbs[128];
  float gbs[128];
  float hypW1s[96];
  float hypb1s[32];
};                                   // total 131840 B

__global__ __launch_bounds__(512) void k_scan2(
    const int* __restrict__ obs, const float* __restrict__ vel,
    const float* __restrict__ hinit, const float* __restrict__ embW,
    const float* __restrict__ velW, const float* __restrict__ velb,
    const float* __restrict__ hW1, const float* __restrict__ hb1,
    const float* __restrict__ gb,
    const unsigned char* __restrict__ w2p, const unsigned char* __restrict__ gwp,
    float* __restrict__ out)
{
  extern __shared__ char smemraw[];
  Scan2Smem* sm = (Scan2Smem*)smemraw;
  const int tid = threadIdx.x;
  const int blk = blockIdx.x;          // 0..15
  const int b0 = blk * 16;

  // static stages
  const unsigned long long* gwu = (const unsigned long long*)gwp;
  for (int idx = tid; idx < 4096; idx += 512) sm->GW[idx] = gwu[idx];
  if (tid < 384) sm->velWs[tid] = velW[tid];
  if (tid < 128) { sm->velbs[tid] = velb[tid]; sm->gbs[tid] = gb[tid]; }
  if (tid < 96)  sm->hypW1s[tid] = hW1[tid];
  if (tid < 32)  sm->hypb1s[tid] = hb1[tid];
  if (tid < 128) {
    float hv = tanhf(hinit[tid]);
    #pragma unroll
    for (int g = 0; g < 16; ++g) sm->h[tid*17+g] = hv;
  }
  __syncthreads();

  const int ln = tid & 63, wv = tid >> 6;
  const int gg = tid & 15;                       // build-phase sample
  const int d0 = ((tid >> 4) & 3) << 3;          // build-phase k-octet base within 32
  const unsigned long long* Au = (const unsigned long long*)w2p + (size_t)wv*64 + ln;

  for (int t = 0; t < TT; ++t) {
    // ---- phase 1: stage i2h, hyp, vel ----
    {
      int g2 = tid >> 5, i0 = (tid & 31) << 2;
      int ov = obs[t*BB + b0 + g2];
      float4 e = *(const float4*)&embW[(size_t)ov*HH + i0];
      sm->i2h[(i0+0)*17+g2] = e.x; sm->i2h[(i0+1)*17+g2] = e.y;
      sm->i2h[(i0+2)*17+g2] = e.z; sm->i2h[(i0+3)*17+g2] = e.w;
      int dh = tid & 31;
      const float* vp = &vel[((size_t)t*BB + b0 + g2)*3];
      float a = vp[0]*sm->hypW1s[dh*3+0] + vp[1]*sm->hypW1s[dh*3+1]
              + vp[2]*sm->hypW1s[dh*3+2] + sm->hypb1s[dh];
      sm->hyps[g2*32+dh] = a / (1.0f + __expf(-a));      // silu
      if (tid < 48) sm->velg[(tid/3)*4 + tid%3] = vel[((size_t)t*BB + b0 + tid/3)*3 + tid%3];
    }
    __syncthreads();
    // ---- phase 2: build U = [h (x) hyp ; h] in fp8 x32, B-fragment layout ----
    {
      float hyp8[8];
      #pragma unroll
      for (int c = 0; c < 8; ++c) hyp8[c] = sm->hyps[gg*32 + d0 + c];
      #pragma unroll
      for (int it = 0; it < 17; ++it) {
        int j = wv + it*8;
        if (j < JBLK) {
          float u[8];
          if (j < 128) {
            float hv = sm->h[j*17+gg] * 32.0f;
            #pragma unroll
            for (int c = 0; c < 8; ++c) u[c] = hv * hyp8[c];
          } else {
            int jj = (j-128)*32 + d0;
            #pragma unroll
            for (int c = 0; c < 8; ++c) u[c] = sm->h[(jj+c)*17+gg] * 32.0f;
          }
          unsigned int w0 = pack4_fp8(u[0], u[1], u[2], u[3]);
          unsigned int w1 = pack4_fp8(u[4], u[5], u[6], u[7]);
          sm->U[j*64 + (tid & 63)] = ((unsigned long long)w1 << 32) | w0;
        }
      }
    }
    __syncthreads();
    // ---- phase 3: hypernet MFMA sweep (132 x 16x16x32 fp8) ----
    {
      f32x4 a0 = {0.f,0.f,0.f,0.f}, a1 = a0, a2 = a0, a3 = a0;
      #pragma unroll 3
      for (int j4 = 0; j4 < JBLK; j4 += 4) {
        long A0 = (long)Au[(size_t)(j4+0)*512]; long B0 = (long)sm->U[(j4+0)*64 + ln];
        long A1 = (long)Au[(size_t)(j4+1)*512]; long B1 = (long)sm->U[(j4+1)*64 + ln];
        long A2 = (long)Au[(size_t)(j4+2)*512]; long B2 = (long)sm->U[(j4+2)*64 + ln];
        long A3 = (long)Au[(size_t)(j4+3)*512]; long B3 = (long)sm->U[(j4+3)*64 + ln];
        a0 = __builtin_amdgcn_mfma_f32_16x16x32_fp8_fp8(A0, B0, a0, 0, 0, 0);
        a1 = __builtin_amdgcn_mfma_f32_16x16x32_fp8_fp8(A1, B1, a1, 0, 0, 0);
        a2 = __builtin_amdgcn_mfma_f32_16x16x32_fp8_fp8(A2, B2, a2, 0, 0, 0);
        a3 = __builtin_amdgcn_mfma_f32_16x16x32_fp8_fp8(A3, B3, a3, 0, 0, 0);
      }
      f32x4 accT = (a0 + a1) + (a2 + a3);
      #pragma unroll
      for (int r = 0; r < 4; ++r) {
        int i = wv*16 + ((ln>>4)<<2) + r, g = ln & 15;
        float p = accT[r] * (1.0f/32768.0f)
                + sm->velg[g*4+0]*sm->velWs[i*3+0] + sm->velg[g*4+1]*sm->velWs[i*3+1]
                + sm->velg[g*4+2]*sm->velWs[i*3+2] + sm->velbs[i];
        sm->pi[i*17+g] = p;
      }
    }
    __syncthreads();
    // ---- phase 4: build X = [pi ; i2h] fp8 x32 into U[0..511] ----
    {
      int kc = tid >> 6;
      int k0 = kc*32 + d0;
      float u[8];
      #pragma unroll
      for (int c = 0; c < 8; ++c) {
        int k = k0 + c;
        u[c] = (k < 128 ? sm->pi[k*17+gg] : sm->i2h[(k-128)*17+gg]) * 32.0f;
      }
      unsigned int w0 = pack4_fp8(u[0], u[1], u[2], u[3]);
      unsigned int w1 = pack4_fp8(u[4], u[5], u[6], u[7]);
      sm->U[kc*64 + (tid & 63)] = ((unsigned long long)w1 << 32) | w0;
    }
    __syncthreads();
    // ---- phase 5: gate MFMA + hidden update ----
    {
      f32x4 ga = {0.f,0.f,0.f,0.f};
      #pragma unroll
      for (int kc = 0; kc < 8; ++kc) {
        long A = (long)sm->GW[(kc*8 + wv)*64 + ln];
        long B = (long)sm->U[kc*64 + ln];
        ga = __builtin_amdgcn_mfma_f32_16x16x32_fp8_fp8(A, B, ga, 0, 0, 0);
      }
      #pragma unroll
      for (int r = 0; r < 4; ++r) {
        int i = wv*16 + ((ln>>4)<<2) + r, g = ln & 15;
        float z = ga[r] * (1.0f/2048.0f) + sm->gbs[i];
        float gt = 1.0f / (1.0f + __expf(-z));
        float pv = sm->pi[i*17+g], ih = sm->i2h[i*17+g];
        float hn = tanhf(gt*pv + (1.0f - gt)*ih);
        sm->h[i*17+g]   = hn;
        sm->i2h[i*17+g] = gt;          // store gate for flush
      }
    }
    __syncthreads();
    // ---- phase 6: coalesced flush of gen / inf_h / gating ----
    {
      int g2 = tid >> 5, i0 = (tid & 31) << 2;
      size_t ob = ((size_t)t*BB + b0 + g2)*HH + i0;
      float4 v;
      v.x = sm->pi[(i0+0)*17+g2]; v.y = sm->pi[(i0+1)*17+g2];
      v.z = sm->pi[(i0+2)*17+g2]; v.w = sm->pi[(i0+3)*17+g2];
      *(float4*)&out[GEN_OFF + ob] = v;
      v.x = sm->h[(i0+0)*17+g2];  v.y = sm->h[(i0+1)*17+g2];
      v.z = sm->h[(i0+2)*17+g2];  v.w = sm->h[(i0+3)*17+g2];
      *(float4*)&out[INFH_OFF + ob] = v;
      v.x = sm->i2h[(i0+0)*17+g2]; v.y = sm->i2h[(i0+1)*17+g2];
      v.z = sm->i2h[(i0+2)*17+g2]; v.w = sm->i2h[(i0+3)*17+g2];
      *(float4*)&out[GATE_OFF + ob] = v;
    }
    __syncthreads();
  }
}

// ---------------- K2a1: q / keys / vals projections (unchanged) ------------------------
struct QkvSmem {
  float wqk[64 * 132];
  float wv[128 * 132];
  float pp[132];
  float hh[132];
  float red[4];
  float stats[2];
};

__global__ __launch_bounds__(256) void k_qkv(const float* __restrict__ out,
    const float* __restrict__ Wqk, const float* __restrict__ Wv,
    float* __restrict__ qbuf, unsigned short* __restrict__ keysBF,
    unsigned short* __restrict__ valsBF)
{
  extern __shared__ char smemraw[];
  QkvSmem* sm = (QkvSmem*)smemraw;
  const int tid = threadIdx.x, b = blockIdx.x;

  for (int idx = tid; idx < 64 * 128; idx += 256) { int o = idx >> 7, j = idx & 127; sm->wqk[o * 132 + j] = Wqk[idx]; }
  for (int idx = tid; idx < 128 * 128; idx += 256) { int o = idx >> 7, j = idx & 127; sm->wv[o * 132 + j] = Wv[idx]; }
  __syncthreads();

  for (int t = 0; t < TT; ++t) {
    if (tid < 128) {
      size_t base = ((size_t)t * BB + b) * HH + tid;
      sm->hh[tid] = out[INFH_OFF + base];
      sm->pp[tid] = tanhf(out[GEN_OFF + base]);
    }
    __syncthreads();
    if (tid < 128) {
      float v = sm->pp[tid];
      float s1 = v, s2 = v * v;
      #pragma unroll
      for (int off = 32; off; off >>= 1) { s1 += __shfl_down(s1, off); s2 += __shfl_down(s2, off); }
      if ((tid & 63) == 0) { sm->red[tid >> 6] = s1; sm->red[2 + (tid >> 6)] = s2; }
    }
    __syncthreads();
    if (tid == 0) {
      float s1 = sm->red[0] + sm->red[1], s2 = sm->red[2] + sm->red[3];
      float m = s1 * (1.0f / 128.0f);
      float var = s2 * (1.0f / 128.0f) - m * m;
      sm->stats[0] = m; sm->stats[1] = rsqrtf(var + 1e-5f);
    }
    __syncthreads();
    if (tid < 128) sm->pp[tid] = (sm->pp[tid] - sm->stats[0]) * sm->stats[1];
    __syncthreads();
    {
      int o = tid;
      if (o < 64) {
        const float* wr = &sm->wqk[o * 132];
        float s = 0.f;
        #pragma unroll 8
        for (int j = 0; j < 128; j += 4) {
          float4 xv = *(const float4*)&sm->pp[j];
          float4 w4 = *(const float4*)&wr[j];
          s += xv.x * w4.x + xv.y * w4.y + xv.z * w4.z + xv.w * w4.w;
        }
        qbuf[((size_t)t * BB + b) * KK + o] = s;
      } else if (o < 128) {
        int kk = o - 64;
        const float* wr = &sm->wqk[kk * 132];
        float s = 0.f;
        #pragma unroll 8
        for (int j = 0; j < 128; j += 4) {
          float4 xv = *(const float4*)&sm->hh[j];
          float4 w4 = *(const float4*)&wr[j];
          s += xv.x * w4.x + xv.y * w4.y + xv.z * w4.z + xv.w * w4.w;
        }
        keysBF[((size_t)t * BB + b) * KK + kk] = f2bf(s);
      } else {
        int vv = o - 128;
        const float* wr = &sm->wv[vv * 132];
        float s = 0.f;
        #pragma unroll 8
        for (int j = 0; j < 128; j += 4) {
          float4 xv = *(const float4*)&sm->hh[j];
          float4 w4 = *(const float4*)&wr[j];
          s += xv.x * w4.x + xv.y * w4.y + xv.z * w4.z + xv.w * w4.w;
        }
        valsBF[((size_t)t * BB + b) * VV + vv] = f2bf(s);
      }
    }
    __syncthreads();
  }
}

// ---------------- K2a2: all scores + max_ip + write-prob MLP (unchanged) ---------------
struct ScoresSmem { float q[128 * 68]; };

__global__ __launch_bounds__(128) void k_scores(const float* __restrict__ qbuf,
    const unsigned short* __restrict__ keysBF, const float* __restrict__ expl,
    const float* __restrict__ mW1, const float* __restrict__ mb1,
    const float* __restrict__ mW2, const float* __restrict__ mb2,
    float* __restrict__ Sg, float* __restrict__ probs)
{
  extern __shared__ char smemraw[];
  ScoresSmem* sm = (ScoresSmem*)smemraw;
  const int tid = threadIdx.x, b = blockIdx.x;

  for (int idx = tid; idx < 128 * 64; idx += 128) {
    int tq = idx >> 6, c = idx & 63;
    sm->q[tq * 68 + c] = qbuf[((size_t)tq * BB + b) * KK + c];
  }
  float kreg[64];
  {
    const uint4* kp = (const uint4*)&keysBF[((size_t)tid * BB + b) * KK];
    #pragma unroll
    for (int qq = 0; qq < 8; ++qq) {
      uint4 kv = kp[qq];
      const unsigned short* ku = (const unsigned short*)&kv;
      #pragma unroll
      for (int c = 0; c < 8; ++c) kreg[qq * 8 + c] = bf2f(ku[c]);
    }
  }
  __syncthreads();

  float* srow = &Sg[(size_t)b * TT * TT];
  for (int tq = 0; tq < TT; ++tq) {
    float s = 0.f;
    #pragma unroll
    for (int c = 0; c < 64; c += 4) {
      float4 qv = *(const float4*)&sm->q[tq * 68 + c];
      s += qv.x * kreg[c] + qv.y * kreg[c + 1] + qv.z * kreg[c + 2] + qv.w * kreg[c + 3];
    }
    srow[(size_t)tq * TT + tid] = s * 0.125f;
  }
  __syncthreads();

  {
    int tq = tid;
    const float* r = &srow[(size_t)tq * TT];
    float mx = -3.0e38f;
    for (int tk = 0; tk < tq; ++tk) mx = fmaxf(mx, r[tk]);
    float f0 = (tq > 0) ? mx : 0.0f;
    float f1 = (float)tq * (1.0f / 128.0f);
    float f2 = expl[(size_t)tq * BB + b];
    float a = 0.f;
    for (int u = 0; u < 200; ++u) {
      float h1 = mW1[u * 3] * f0 + mW1[u * 3 + 1] * f1 + mW1[u * 3 + 2] * f2 + mb1[u];
      h1 = (h1 > 0.f) ? h1 : 0.1f * h1;
      a += mW2[u] * h1;
    }
    float p = 1.0f / (1.0f + __expf(-(a + mb2[0])));
    probs[(size_t)b * TT + tq] = p;
  }
}

// ---------------- K2b: softmax·probs·vals -> LN -> logits -> preds (unchanged) ---------
struct AttnSmem {
  float w[32 * 132];
  float mem[32 * 132];
  float pw[128 * 132];
};

__global__ __launch_bounds__(256) void k_attn(const float* __restrict__ Sg,
    const float* __restrict__ probs, const unsigned short* __restrict__ valsBF,
    const float* __restrict__ pW, const float* __restrict__ pb,
    float* __restrict__ out)
{
  extern __shared__ char smemraw[];
  AttnSmem* sm = (AttnSmem*)smemraw;
  const int tid = threadIdx.x;
  const int t = blockIdx.x >> 3, g = blockIdx.x & 7;
  const int bloc = tid >> 3, s8 = tid & 7;
  const int b = g * 32 + bloc;

  float acc[16];
  #pragma unroll
  for (int c = 0; c < 16; ++c) acc[c] = 0.f;

  float inv = 0.f;
  if (t > 0) {
    const float* srow = &Sg[((size_t)b * TT + t) * TT];
    float mx = -3.0e38f;
    for (int tk = s8; tk < t; tk += 8) mx = fmaxf(mx, srow[tk]);
    #pragma unroll
    for (int off = 4; off; off >>= 1) mx = fmaxf(mx, __shfl_xor(mx, off, 8));
    float es = 0.f;
    for (int tk = s8; tk < t; tk += 8) {
      float e = __expf(srow[tk] - mx);
      es += e;
      sm->w[bloc * 132 + tk] = e * probs[(size_t)b * TT + tk];
    }
    #pragma unroll
    for (int off = 4; off; off >>= 1) es += __shfl_xor(es, off, 8);
    inv = 1.0f / es;
  }
  __syncthreads();
  if (t > 0) {
    for (int tk = 0; tk < t; ++tk) {
      float wv = sm->w[bloc * 132 + tk] * inv;
      const uint4* vp = (const uint4*)&valsBF[((size_t)tk * BB + b) * VV + s8 * 16];
      uint4 v0 = vp[0], v1 = vp[1];
      const unsigned short* u0 = (const unsigned short*)&v0;
      const unsigned short* u1 = (const unsigned short*)&v1;
      #pragma unroll
      for (int c = 0; c < 8; ++c) acc[c] += wv * bf2f(u0[c]);
      #pragma unroll
      for (int c = 0; c < 8; ++c) acc[8 + c] += wv * bf2f(u1[c]);
    }
  }
  float s1 = 0.f, s2 = 0.f;
  #pragma unroll
  for (int c = 0; c < 16; ++c) { s1 += acc[c]; s2 += acc[c] * acc[c]; }
  #pragma unroll
  for (int off = 4; off; off >>= 1) { s1 += __shfl_xor(s1, off, 8); s2 += __shfl_xor(s2, off, 8); }
  float m = s1 * (1.0f / 128.0f);
  float var = s2 * (1.0f / 128.0f) - m * m;
  float sc = rsqrtf(var + 1e-5f);
  #pragma unroll
  for (int c = 0; c < 16; ++c) sm->mem[bloc * 132 + s8 * 16 + c] = (acc[c] - m) * sc;
  __syncthreads();

  const int og = tid >> 5, bl2 = tid & 31;
  const int b2 = g * 32 + bl2;
  for (int st = 0; st < 4; ++st) {
    for (int idx = tid; idx < 128 * 128; idx += 256) {
      int o = idx >> 7, i = idx & 127;
      sm->pw[o * 132 + i] = pW[((size_t)(st * 128 + o)) * HH + i];
    }
    __syncthreads();
    #pragma unroll
    for (int ob = 0; ob < 4; ++ob) {
      int oo = og * 16 + ob * 4;
      float a0 = pb[st * 128 + oo], a1 = pb[st * 128 + oo + 1];
      float a2 = pb[st * 128 + oo + 2], a3 = pb[st * 128 + oo + 3];
      for (int i = 0; i < 128; i += 4) {
        float4 mv = *(const float4*)&sm->mem[bl2 * 132 + i];
        float4 w0 = *(const float4*)&sm->pw[(oo + 0) * 132 + i];
        float4 w1 = *(const float4*)&sm->pw[(oo + 1) * 132 + i];
        float4 w2 = *(const float4*)&sm->pw[(oo + 2) * 132 + i];
        float4 w3 = *(const float4*)&sm->pw[(oo + 3) * 132 + i];
        a0 += mv.x * w0.x + mv.y * w0.y + mv.z * w0.z + mv.w * w0.w;
        a1 += mv.x * w1.x + mv.y * w1.y + mv.z * w1.z + mv.w * w1.w;
        a2 += mv.x * w2.x + mv.y * w2.y + mv.z * w2.z + mv.w * w2.w;
        a3 += mv.x * w3.x + mv.y * w3.y + mv.z * w3.z + mv.w * w3.w;
      }
      size_t base = LOGIT_OFF + ((size_t)t * BB + b2) * OO + st * 128 + oo;
      out[base] = a0; out[base + 1] = a1; out[base + 2] = a2; out[base + 3] = a3;
    }
    __syncthreads();
  }
  {
    const float* lrow = &out[LOGIT_OFF + ((size_t)t * BB + b) * OO];
    float mx = -3.0e38f;
    for (int o = s8; o < OO; o += 8) mx = fmaxf(mx, lrow[o]);
    #pragma unroll
    for (int off = 4; off; off >>= 1) mx = fmaxf(mx, __shfl_xor(mx, off, 8));
    float zs = 0.f;
    for (int o = s8; o < OO; o += 8) zs += __expf(lrow[o] - mx);
    #pragma unroll
    for (int off = 4; off; off >>= 1) zs += __shfl_xor(zs, off, 8);
    float zi = 1.0f / zs;
    float* prow = &out[PRED_OFF + ((size_t)t * BB + b) * OO];
    for (int o = s8; o < OO; o += 8) prow[o] = __expf(lrow[o] - mx) * zi;
  }
}

// ---------------- launcher -------------------------------------------------------------
extern "C" void kernel_launch(void* const* d_in, const int* in_sizes, int n_in,
                              void* d_out, int out_size, void* d_ws, size_t ws_size,
                              hipStream_t stream) {
  (void)in_sizes; (void)n_in; (void)out_size; (void)ws_size;
  const int*   obs   = (const int*)d_in[0];
  const float* vel   = (const float*)d_in[1];
  const float* expl  = (const float*)d_in[2];
  const float* hinit = (const float*)d_in[3];
  const float* embW  = (const float*)d_in[4];
  const float* velW  = (const float*)d_in[5];
  const float* velb  = (const float*)d_in[6];
  const float* hW1   = (const float*)d_in[7];
  const float* hb1   = (const float*)d_in[8];
  const float* hW2   = (const float*)d_in[9];
  const float* hb2   = (const float*)d_in[10];
  const float* gW    = (const float*)d_in[11];
  const float* gb    = (const float*)d_in[12];
  const float* pW    = (const float*)d_in[13];
  const float* pb    = (const float*)d_in[14];
  const float* mW1   = (const float*)d_in[15];
  const float* mb1   = (const float*)d_in[16];
  const float* mW2   = (const float*)d_in[17];
  const float* mb2   = (const float*)d_in[18];
  const float* Wqk   = (const float*)d_in[19];
  const float* Wv    = (const float*)d_in[20];
  float* out = (float*)d_out;
  char* ws = (char*)d_ws;

  unsigned char*  w2p    = (unsigned char*)(ws + 0);            // 540,672 B
  unsigned char*  gwp    = (unsigned char*)(ws + 589824);       // 32,768 B
  float*          qbuf   = (float*)(ws + 1048576);              // 8 MB
  unsigned short* keysBF = (unsigned short*)(ws + 9437184);     // 4 MB
  unsigned short* valsBF = (unsigned short*)(ws + 13631488);    // 8 MB
  float*          Sg     = (float*)(ws + 22020096);             // 16 MB
  float*          probs  = (float*)(ws + 38797312);             // 128 KB

  k_pack  <<<dim3(560),  dim3(256), 0,                   stream>>>(hW2, hb2, gW, w2p, gwp);
  k_scan2 <<<dim3(16),   dim3(512), sizeof(Scan2Smem),   stream>>>(obs, vel, hinit, embW, velW, velb,
                                                                   hW1, hb1, gb, w2p, gwp, out);
  k_qkv   <<<dim3(256),  dim3(256), sizeof(QkvSmem),     stream>>>(out, Wqk, Wv, qbuf, keysBF, valsBF);
  k_scores<<<dim3(256),  dim3(128), sizeof(ScoresSmem),  stream>>>(qbuf, keysBF, expl, mW1, mb1, mW2, mb2,
                                                                   Sg, probs);
  k_attn  <<<dim3(1024), dim3(256), sizeof(AttnSmem),    stream>>>(Sg, probs, valsBF, pW, pb, out);
}

// Round 3
// 2884.699 us; speedup vs baseline: 1.1376x; 1.1376x over previous
//
#include <hip/hip_runtime.h>

#ifndef __has_builtin
#define __has_builtin(x) 0
#endif

#define DEV static __device__ __forceinline__

// problem dims
#define TT 128
#define BB 256
#define HH 128
#define KK 64
#define VV 128
#define OO 512
#define JBLK 132                // 128 hypernet j-blocks + 4 blocks for hyp_b2 (bias @ h)
#define KEXT (JBLK*32)          // 4224
#define NJR 64                  // j-blocks of A held in registers (2 VGPR each)
#define NSTR (JBLK-NJR)         // 68 streamed j-blocks per step

static const size_t PRED_OFF  = 0;
static const size_t LOGIT_OFF = (size_t)TT*BB*OO;                  // 16777216
static const size_t INFH_OFF  = LOGIT_OFF + (size_t)TT*BB*OO;      // 33554432
static const size_t GEN_OFF   = INFH_OFF + (size_t)TT*BB*HH;       // 37748736
static const size_t GATE_OFF  = GEN_OFF + (size_t)TT*BB*HH;        // 41943040

typedef float f32x4 __attribute__((ext_vector_type(4)));

DEV unsigned short f2bf(float x){
  unsigned int u = __float_as_uint(x);
  u = (u + 0x7fffu + ((u >> 16) & 1u)) >> 16;   // RNE
  return (unsigned short)u;
}
DEV float bf2f(unsigned short v){ return __uint_as_float(((unsigned int)v) << 16); }

// ---------------- fp8 e4m3 helpers ----------------------------------------------------
DEV unsigned char enc8_sw(float x){
  unsigned int u = __float_as_uint(x);
  unsigned int s = (u >> 24) & 0x80u;
  int e = (int)((u >> 23) & 0xffu) - 127;
  unsigned int m = u & 0x7fffffu;
  if (((u >> 23) & 0xffu) == 0) return (unsigned char)s;
  if (e < -10) return (unsigned char)s;
  if (e >= -6) {
    unsigned int mant = m >> 20, rem = m & 0xfffffu;
    if (rem > 0x80000u || (rem == 0x80000u && (mant & 1u))) mant++;
    unsigned int ee = (unsigned int)(e + 7);
    if (mant == 8u) { mant = 0u; ee++; }
    if (ee >= 15u) return (unsigned char)(s | 0x7Eu);
    return (unsigned char)(s | (ee << 3) | mant);
  }
  unsigned int full = 0x800000u | m;
  int sh = 20 + (-6 - e);
  unsigned int mant = full >> sh;
  unsigned int rem  = full & ((1u << sh) - 1u);
  unsigned int halfv = 1u << (sh - 1);
  if (rem > halfv || (rem == halfv && (mant & 1u))) mant++;
  if (mant >= 8u) return (unsigned char)(s | (1u << 3));
  return (unsigned char)(s | mant);
}

DEV unsigned char enc8(float v){
#if __has_builtin(__builtin_amdgcn_cvt_pk_fp8_f32)
  int r = __builtin_amdgcn_cvt_pk_fp8_f32(v, v, 0, false);
  return (unsigned char)(r & 0xff);
#else
  return enc8_sw(v);
#endif
}

DEV unsigned int pack4_fp8(float a, float b, float c, float d){
#if __has_builtin(__builtin_amdgcn_cvt_pk_fp8_f32)
  int w = __builtin_amdgcn_cvt_pk_fp8_f32(a, b, 0, false);
  w = __builtin_amdgcn_cvt_pk_fp8_f32(c, d, w, true);
  return (unsigned int)w;
#else
  return (unsigned int)enc8_sw(a) | ((unsigned int)enc8_sw(b)<<8)
       | ((unsigned int)enc8_sw(c)<<16) | ((unsigned int)enc8_sw(d)<<24);
#endif
}

// ---------------- K0: pack W2ext and gate_W to fp8 MFMA-fragment layout ----------------
// W2ext byte (j, w, l, c) at ((j*8+w)*64+l)*8 + c:
//   i = w*16 + (l&15);  k = j*32 + (l>>4)*8 + c  (A-fragment order of 16x16x32 fp8 MFMA)
//   j<128: value = hyp_W2[i*128+j][k%32] * 1024 ;  j>=128: value = hyp_b2[i*128 + (j-128)*32 + k%32] * 1024
// gate_W byte (kc, w, l, c) at ((kc*8+w)*64+l)*8 + c:
//   i = w*16 + (l&15);  k = kc*32 + (l>>4)*8 + c ; value = gW[i*256+k] * 64
#define W2_DWORDS 135168
#define GW_DWORDS 8192
__global__ __launch_bounds__(256) void k_pack(const float* __restrict__ hW2,
                                              const float* __restrict__ hb2,
                                              const float* __restrict__ gW,
                                              unsigned char* __restrict__ w2p,
                                              unsigned char* __restrict__ gwp){
  int D = blockIdx.x * 256 + threadIdx.x;
  if (D < W2_DWORDS) {
    int flat = D * 4;
    int l  = (flat >> 3) & 63;
    int w  = (flat >> 9) & 7;
    int j  = flat >> 12;
    int cb = flat & 7;              // 0 or 4
    int i  = w*16 + (l & 15);
    int db = ((l >> 4) << 3) + cb;
    unsigned int outw = 0;
    for (int cc = 0; cc < 4; ++cc) {
      int d = db + cc;              // 0..31
      float v;
      if (j < 128) v = hW2[((size_t)i*128 + j)*32 + d];
      else         v = hb2[(size_t)i*128 + (j-128)*32 + d];
      outw |= ((unsigned int)enc8(v * 1024.0f)) << (8*cc);
    }
    ((unsigned int*)w2p)[D] = outw;
  } else if (D < W2_DWORDS + GW_DWORDS) {
    int Dg = D - W2_DWORDS;
    int flat = Dg * 4;
    int l  = (flat >> 3) & 63;
    int w  = (flat >> 9) & 7;
    int kc = flat >> 12;
    int cb = flat & 7;
    int i  = w*16 + (l & 15);
    int k0 = kc*32 + ((l >> 4) << 3) + cb;
    unsigned int outw = 0;
    for (int cc = 0; cc < 4; ++cc)
      outw |= ((unsigned int)enc8(gW[(size_t)i*256 + k0 + cc] * 64.0f)) << (8*cc);
    ((unsigned int*)gwp)[Dg] = outw;
  }
}

// ---------------- K1: sequential scan, MFMA + A-in-registers (16 blocks x 16 samples) --
struct Scan3Smem {
  unsigned long long U[JBLK*64];    // 67584 B — B-fragments (fp8 x32); aliased for gate X
  float h[128*17];                  // stride-17 padded [i][g]
  float pi[128*17];
  float i2h[128*17];                // raw i2h; overwritten with gate in phase 5
  float hyps[16*32];
  float velg[64];                   // [g][c] pad 4
  float velWs[384];
  float velbs[128];
  float gbs[128];
  float hypW1s[96];
  float hypb1s[32];
};                                   // ~99 KB

__global__ __launch_bounds__(512) void k_scan3(
    const int* __restrict__ obs, const float* __restrict__ vel,
    const float* __restrict__ hinit, const float* __restrict__ embW,
    const float* __restrict__ velW, const float* __restrict__ velb,
    const float* __restrict__ hW1, const float* __restrict__ hb1,
    const float* __restrict__ gb,
    const unsigned char* __restrict__ w2p, const unsigned char* __restrict__ gwp,
    float* __restrict__ out)
{
  extern __shared__ char smemraw[];
  Scan3Smem* sm = (Scan3Smem*)smemraw;
  const int tid = threadIdx.x;
  const int blk = blockIdx.x;          // 0..15
  const int b0 = blk * 16;

  if (tid < 384) sm->velWs[tid] = velW[tid];
  if (tid < 128) { sm->velbs[tid] = velb[tid]; sm->gbs[tid] = gb[tid]; }
  if (tid < 96)  sm->hypW1s[tid] = hW1[tid];
  if (tid < 32)  sm->hypb1s[tid] = hb1[tid];
  if (tid < 128) {
    float hv = tanhf(hinit[tid]);
    #pragma unroll
    for (int g = 0; g < 16; ++g) sm->h[tid*17+g] = hv;
  }
  __syncthreads();

  const int ln = tid & 63, wv = tid >> 6;
  const int gg = tid & 15;                       // build-phase sample
  const int d0 = ((tid >> 4) & 3) << 3;          // build-phase k-octet base within 32
  const unsigned long long* Au = (const unsigned long long*)w2p + (size_t)wv*64 + ln;
  const unsigned long long* Gu = (const unsigned long long*)gwp;

  // loop-invariant register caches: A-fragments for j-blocks [0, NJR) and all gate_W
  unsigned long long Areg[NJR];
  #pragma unroll
  for (int r = 0; r < NJR; ++r) Areg[r] = Au[(size_t)r*512];
  unsigned long long GWreg[8];
  #pragma unroll
  for (int kc = 0; kc < 8; ++kc) GWreg[kc] = Gu[(size_t)(kc*8 + wv)*64 + ln];

  for (int t = 0; t < TT; ++t) {
    // ---- phase 1: stage i2h, hyp, vel ----
    {
      int g2 = tid >> 5, i0 = (tid & 31) << 2;
      int ov = obs[t*BB + b0 + g2];
      float4 e = *(const float4*)&embW[(size_t)ov*HH + i0];
      sm->i2h[(i0+0)*17+g2] = e.x; sm->i2h[(i0+1)*17+g2] = e.y;
      sm->i2h[(i0+2)*17+g2] = e.z; sm->i2h[(i0+3)*17+g2] = e.w;
      int dh = tid & 31;
      const float* vp = &vel[((size_t)t*BB + b0 + g2)*3];
      float a = vp[0]*sm->hypW1s[dh*3+0] + vp[1]*sm->hypW1s[dh*3+1]
              + vp[2]*sm->hypW1s[dh*3+2] + sm->hypb1s[dh];
      sm->hyps[g2*32+dh] = a / (1.0f + __expf(-a));      // silu
      if (tid < 48) sm->velg[(tid/3)*4 + tid%3] = vel[((size_t)t*BB + b0 + tid/3)*3 + tid%3];
    }
    __syncthreads();
    // ---- phase 2: build U = [h (x) hyp ; h] in fp8 x32, B-fragment layout ----
    {
      float hyp8[8];
      #pragma unroll
      for (int c = 0; c < 8; ++c) hyp8[c] = sm->hyps[gg*32 + d0 + c];
      #pragma unroll
      for (int it = 0; it < 17; ++it) {
        int j = wv + it*8;
        if (j < JBLK) {
          float u[8];
          if (j < 128) {
            float hv = sm->h[j*17+gg] * 32.0f;
            #pragma unroll
            for (int c = 0; c < 8; ++c) u[c] = hv * hyp8[c];
          } else {
            int jj = (j-128)*32 + d0;
            #pragma unroll
            for (int c = 0; c < 8; ++c) u[c] = sm->h[(jj+c)*17+gg] * 32.0f;
          }
          unsigned int w0 = pack4_fp8(u[0], u[1], u[2], u[3]);
          unsigned int w1 = pack4_fp8(u[4], u[5], u[6], u[7]);
          sm->U[j*64 + (tid & 63)] = ((unsigned long long)w1 << 32) | w0;
        }
      }
    }
    __syncthreads();
    // ---- phase 3: hypernet MFMA sweep (NJR from regs + NSTR streamed) ----
    {
      // issue first streamed loads immediately (overlap with register-part MFMAs)
      unsigned long long As[8];
      #pragma unroll
      for (int p = 0; p < 8; ++p) As[p] = Au[(size_t)(NJR+p)*512];

      f32x4 acc[4];
      #pragma unroll
      for (int r = 0; r < 4; ++r) acc[r] = (f32x4){0.f,0.f,0.f,0.f};

      #pragma unroll
      for (int j4 = 0; j4 < NJR; j4 += 4) {
        long B0 = (long)sm->U[(j4+0)*64 + ln];
        long B1 = (long)sm->U[(j4+1)*64 + ln];
        long B2 = (long)sm->U[(j4+2)*64 + ln];
        long B3 = (long)sm->U[(j4+3)*64 + ln];
        acc[0] = __builtin_amdgcn_mfma_f32_16x16x32_fp8_fp8((long)Areg[j4+0], B0, acc[0], 0, 0, 0);
        acc[1] = __builtin_amdgcn_mfma_f32_16x16x32_fp8_fp8((long)Areg[j4+1], B1, acc[1], 0, 0, 0);
        acc[2] = __builtin_amdgcn_mfma_f32_16x16x32_fp8_fp8((long)Areg[j4+2], B2, acc[2], 0, 0, 0);
        acc[3] = __builtin_amdgcn_mfma_f32_16x16x32_fp8_fp8((long)Areg[j4+3], B3, acc[3], 0, 0, 0);
      }
      // streamed tail with rolling depth-8 register pipeline (fully unrolled: static idx)
      #pragma unroll
      for (int c = 0; c < NSTR; ++c) {
        long B = (long)sm->U[(NJR+c)*64 + ln];
        acc[c & 3] = __builtin_amdgcn_mfma_f32_16x16x32_fp8_fp8((long)As[c & 7], B, acc[c & 3], 0, 0, 0);
        if (c + 8 < NSTR) As[c & 7] = Au[(size_t)(NJR+c+8)*512];
      }
      f32x4 accT = (acc[0] + acc[1]) + (acc[2] + acc[3]);
      #pragma unroll
      for (int r = 0; r < 4; ++r) {
        int i = wv*16 + ((ln>>4)<<2) + r, g = ln & 15;
        float p = accT[r] * (1.0f/32768.0f)
                + sm->velg[g*4+0]*sm->velWs[i*3+0] + sm->velg[g*4+1]*sm->velWs[i*3+1]
                + sm->velg[g*4+2]*sm->velWs[i*3+2] + sm->velbs[i];
        sm->pi[i*17+g] = p;
      }
    }
    __syncthreads();
    // ---- phase 4: build X = [pi ; i2h] fp8 x32 into U[0..511] ----
    {
      int kc = tid >> 6;
      int k0 = kc*32 + d0;
      float u[8];
      #pragma unroll
      for (int c = 0; c < 8; ++c) {
        int k = k0 + c;
        u[c] = (k < 128 ? sm->pi[k*17+gg] : sm->i2h[(k-128)*17+gg]) * 32.0f;
      }
      unsigned int w0 = pack4_fp8(u[0], u[1], u[2], u[3]);
      unsigned int w1 = pack4_fp8(u[4], u[5], u[6], u[7]);
      sm->U[kc*64 + (tid & 63)] = ((unsigned long long)w1 << 32) | w0;
    }
    __syncthreads();
    // ---- phase 5: gate MFMA (gate_W from regs) + hidden update ----
    {
      f32x4 ga = {0.f,0.f,0.f,0.f};
      #pragma unroll
      for (int kc = 0; kc < 8; ++kc) {
        long B = (long)sm->U[kc*64 + ln];
        ga = __builtin_amdgcn_mfma_f32_16x16x32_fp8_fp8((long)GWreg[kc], B, ga, 0, 0, 0);
      }
      #pragma unroll
      for (int r = 0; r < 4; ++r) {
        int i = wv*16 + ((ln>>4)<<2) + r, g = ln & 15;
        float z = ga[r] * (1.0f/2048.0f) + sm->gbs[i];
        float gt = 1.0f / (1.0f + __expf(-z));
        float pv = sm->pi[i*17+g], ih = sm->i2h[i*17+g];
        float hn = tanhf(gt*pv + (1.0f - gt)*ih);
        sm->h[i*17+g]   = hn;
        sm->i2h[i*17+g] = gt;          // store gate for flush
      }
    }
    __syncthreads();
    // ---- phase 6: coalesced flush of gen / inf_h / gating ----
    {
      int g2 = tid >> 5, i0 = (tid & 31) << 2;
      size_t ob = ((size_t)t*BB + b0 + g2)*HH + i0;
      float4 v;
      v.x = sm->pi[(i0+0)*17+g2]; v.y = sm->pi[(i0+1)*17+g2];
      v.z = sm->pi[(i0+2)*17+g2]; v.w = sm->pi[(i0+3)*17+g2];
      *(float4*)&out[GEN_OFF + ob] = v;
      v.x = sm->h[(i0+0)*17+g2];  v.y = sm->h[(i0+1)*17+g2];
      v.z = sm->h[(i0+2)*17+g2];  v.w = sm->h[(i0+3)*17+g2];
      *(float4*)&out[INFH_OFF + ob] = v;
      v.x = sm->i2h[(i0+0)*17+g2]; v.y = sm->i2h[(i0+1)*17+g2];
      v.z = sm->i2h[(i0+2)*17+g2]; v.w = sm->i2h[(i0+3)*17+g2];
      *(float4*)&out[GATE_OFF + ob] = v;
    }
    __syncthreads();
  }
}

// ---------------- K2a1: q / keys / vals projections (unchanged) ------------------------
struct QkvSmem {
  float wqk[64 * 132];
  float wv[128 * 132];
  float pp[132];
  float hh[132];
  float red[4];
  float stats[2];
};

__global__ __launch_bounds__(256) void k_qkv(const float* __restrict__ out,
    const float* __restrict__ Wqk, const float* __restrict__ Wv,
    float* __restrict__ qbuf, unsigned short* __restrict__ keysBF,
    unsigned short* __restrict__ valsBF)
{
  extern __shared__ char smemraw[];
  QkvSmem* sm = (QkvSmem*)smemraw;
  const int tid = threadIdx.x, b = blockIdx.x;

  for (int idx = tid; idx < 64 * 128; idx += 256) { int o = idx >> 7, j = idx & 127; sm->wqk[o * 132 + j] = Wqk[idx]; }
  for (int idx = tid; idx < 128 * 128; idx += 256) { int o = idx >> 7, j = idx & 127; sm->wv[o * 132 + j] = Wv[idx]; }
  __syncthreads();

  for (int t = 0; t < TT; ++t) {
    if (tid < 128) {
      size_t base = ((size_t)t * BB + b) * HH + tid;
      sm->hh[tid] = out[INFH_OFF + base];
      sm->pp[tid] = tanhf(out[GEN_OFF + base]);
    }
    __syncthreads();
    if (tid < 128) {
      float v = sm->pp[tid];
      float s1 = v, s2 = v * v;
      #pragma unroll
      for (int off = 32; off; off >>= 1) { s1 += __shfl_down(s1, off); s2 += __shfl_down(s2, off); }
      if ((tid & 63) == 0) { sm->red[tid >> 6] = s1; sm->red[2 + (tid >> 6)] = s2; }
    }
    __syncthreads();
    if (tid == 0) {
      float s1 = sm->red[0] + sm->red[1], s2 = sm->red[2] + sm->red[3];
      float m = s1 * (1.0f / 128.0f);
      float var = s2 * (1.0f / 128.0f) - m * m;
      sm->stats[0] = m; sm->stats[1] = rsqrtf(var + 1e-5f);
    }
    __syncthreads();
    if (tid < 128) sm->pp[tid] = (sm->pp[tid] - sm->stats[0]) * sm->stats[1];
    __syncthreads();
    {
      int o = tid;
      if (o < 64) {
        const float* wr = &sm->wqk[o * 132];
        float s = 0.f;
        #pragma unroll 8
        for (int j = 0; j < 128; j += 4) {
          float4 xv = *(const float4*)&sm->pp[j];
          float4 w4 = *(const float4*)&wr[j];
          s += xv.x * w4.x + xv.y * w4.y + xv.z * w4.z + xv.w * w4.w;
        }
        qbuf[((size_t)t * BB + b) * KK + o] = s;
      } else if (o < 128) {
        int kk = o - 64;
        const float* wr = &sm->wqk[kk * 132];
        float s = 0.f;
        #pragma unroll 8
        for (int j = 0; j < 128; j += 4) {
          float4 xv = *(const float4*)&sm->hh[j];
          float4 w4 = *(const float4*)&wr[j];
          s += xv.x * w4.x + xv.y * w4.y + xv.z * w4.z + xv.w * w4.w;
        }
        keysBF[((size_t)t * BB + b) * KK + kk] = f2bf(s);
      } else {
        int vv = o - 128;
        const float* wr = &sm->wv[vv * 132];
        float s = 0.f;
        #pragma unroll 8
        for (int j = 0; j < 128; j += 4) {
          float4 xv = *(const float4*)&sm->hh[j];
          float4 w4 = *(const float4*)&wr[j];
          s += xv.x * w4.x + xv.y * w4.y + xv.z * w4.z + xv.w * w4.w;
        }
        valsBF[((size_t)t * BB + b) * VV + vv] = f2bf(s);
      }
    }
    __syncthreads();
  }
}

// ---------------- K2a2: all scores + max_ip + write-prob MLP (unchanged) ---------------
struct ScoresSmem { float q[128 * 68]; };

__global__ __launch_bounds__(128) void k_scores(const float* __restrict__ qbuf,
    const unsigned short* __restrict__ keysBF, const float* __restrict__ expl,
    const float* __restrict__ mW1, const float* __restrict__ mb1,
    const float* __restrict__ mW2, const float* __restrict__ mb2,
    float* __restrict__ Sg, float* __restrict__ probs)
{
  extern __shared__ char smemraw[];
  ScoresSmem* sm = (ScoresSmem*)smemraw;
  const int tid = threadIdx.x, b = blockIdx.x;

  for (int idx = tid; idx < 128 * 64; idx += 128) {
    int tq = idx >> 6, c = idx & 63;
    sm->q[tq * 68 + c] = qbuf[((size_t)tq * BB + b) * KK + c];
  }
  float kreg[64];
  {
    const uint4* kp = (const uint4*)&keysBF[((size_t)tid * BB + b) * KK];
    #pragma unroll
    for (int qq = 0; qq < 8; ++qq) {
      uint4 kv = kp[qq];
      const unsigned short* ku = (const unsigned short*)&kv;
      #pragma unroll
      for (int c = 0; c < 8; ++c) kreg[qq * 8 + c] = bf2f(ku[c]);
    }
  }
  __syncthreads();

  float* srow = &Sg[(size_t)b * TT * TT];
  for (int tq = 0; tq < TT; ++tq) {
    float s = 0.f;
    #pragma unroll
    for (int c = 0; c < 64; c += 4) {
      float4 qv = *(const float4*)&sm->q[tq * 68 + c];
      s += qv.x * kreg[c] + qv.y * kreg[c + 1] + qv.z * kreg[c + 2] + qv.w * kreg[c + 3];
    }
    srow[(size_t)tq * TT + tid] = s * 0.125f;
  }
  __syncthreads();

  {
    int tq = tid;
    const float* r = &srow[(size_t)tq * TT];
    float mx = -3.0e38f;
    for (int tk = 0; tk < tq; ++tk) mx = fmaxf(mx, r[tk]);
    float f0 = (tq > 0) ? mx : 0.0f;
    float f1 = (float)tq * (1.0f / 128.0f);
    float f2 = expl[(size_t)tq * BB + b];
    float a = 0.f;
    for (int u = 0; u < 200; ++u) {
      float h1 = mW1[u * 3] * f0 + mW1[u * 3 + 1] * f1 + mW1[u * 3 + 2] * f2 + mb1[u];
      h1 = (h1 > 0.f) ? h1 : 0.1f * h1;
      a += mW2[u] * h1;
    }
    float p = 1.0f / (1.0f + __expf(-(a + mb2[0])));
    probs[(size_t)b * TT + tq] = p;
  }
}

// ---------------- K2b: softmax·probs·vals -> LN -> logits -> preds (unchanged) ---------
struct AttnSmem {
  float w[32 * 132];
  float mem[32 * 132];
  float pw[128 * 132];
};

__global__ __launch_bounds__(256) void k_attn(const float* __restrict__ Sg,
    const float* __restrict__ probs, const unsigned short* __restrict__ valsBF,
    const float* __restrict__ pW, const float* __restrict__ pb,
    float* __restrict__ out)
{
  extern __shared__ char smemraw[];
  AttnSmem* sm = (AttnSmem*)smemraw;
  const int tid = threadIdx.x;
  const int t = blockIdx.x >> 3, g = blockIdx.x & 7;
  const int bloc = tid >> 3, s8 = tid & 7;
  const int b = g * 32 + bloc;

  float acc[16];
  #pragma unroll
  for (int c = 0; c < 16; ++c) acc[c] = 0.f;

  float inv = 0.f;
  if (t > 0) {
    const float* srow = &Sg[((size_t)b * TT + t) * TT];
    float mx = -3.0e38f;
    for (int tk = s8; tk < t; tk += 8) mx = fmaxf(mx, srow[tk]);
    #pragma unroll
    for (int off = 4; off; off >>= 1) mx = fmaxf(mx, __shfl_xor(mx, off, 8));
    float es = 0.f;
    for (int tk = s8; tk < t; tk += 8) {
      float e = __expf(srow[tk] - mx);
      es += e;
      sm->w[bloc * 132 + tk] = e * probs[(size_t)b * TT + tk];
    }
    #pragma unroll
    for (int off = 4; off; off >>= 1) es += __shfl_xor(es, off, 8);
    inv = 1.0f / es;
  }
  __syncthreads();
  if (t > 0) {
    for (int tk = 0; tk < t; ++tk) {
      float wv = sm->w[bloc * 132 + tk] * inv;
      const uint4* vp = (const uint4*)&valsBF[((size_t)tk * BB + b) * VV + s8 * 16];
      uint4 v0 = vp[0], v1 = vp[1];
      const unsigned short* u0 = (const unsigned short*)&v0;
      const unsigned short* u1 = (const unsigned short*)&v1;
      #pragma unroll
      for (int c = 0; c < 8; ++c) acc[c] += wv * bf2f(u0[c]);
      #pragma unroll
      for (int c = 0; c < 8; ++c) acc[8 + c] += wv * bf2f(u1[c]);
    }
  }
  float s1 = 0.f, s2 = 0.f;
  #pragma unroll
  for (int c = 0; c < 16; ++c) { s1 += acc[c]; s2 += acc[c] * acc[c]; }
  #pragma unroll
  for (int off = 4; off; off >>= 1) { s1 += __shfl_xor(s1, off, 8); s2 += __shfl_xor(s2, off, 8); }
  float m = s1 * (1.0f / 128.0f);
  float var = s2 * (1.0f / 128.0f) - m * m;
  float sc = rsqrtf(var + 1e-5f);
  #pragma unroll
  for (int c = 0; c < 16; ++c) sm->mem[bloc * 132 + s8 * 16 + c] = (acc[c] - m) * sc;
  __syncthreads();

  const int og = tid >> 5, bl2 = tid & 31;
  const int b2 = g * 32 + bl2;
  for (int st = 0; st < 4; ++st) {
    for (int idx = tid; idx < 128 * 128; idx += 256) {
      int o = idx >> 7, i = idx & 127;
      sm->pw[o * 132 + i] = pW[((size_t)(st * 128 + o)) * HH + i];
    }
    __syncthreads();
    #pragma unroll
    for (int ob = 0; ob < 4; ++ob) {
      int oo = og * 16 + ob * 4;
      float a0 = pb[st * 128 + oo], a1 = pb[st * 128 + oo + 1];
      float a2 = pb[st * 128 + oo + 2], a3 = pb[st * 128 + oo + 3];
      for (int i = 0; i < 128; i += 4) {
        float4 mv = *(const float4*)&sm->mem[bl2 * 132 + i];
        float4 w0 = *(const float4*)&sm->pw[(oo + 0) * 132 + i];
        float4 w1 = *(const float4*)&sm->pw[(oo + 1) * 132 + i];
        float4 w2 = *(const float4*)&sm->pw[(oo + 2) * 132 + i];
        float4 w3 = *(const float4*)&sm->pw[(oo + 3) * 132 + i];
        a0 += mv.x * w0.x + mv.y * w0.y + mv.z * w0.z + mv.w * w0.w;
        a1 += mv.x * w1.x + mv.y * w1.y + mv.z * w1.z + mv.w * w1.w;
        a2 += mv.x * w2.x + mv.y * w2.y + mv.z * w2.z + mv.w * w2.w;
        a3 += mv.x * w3.x + mv.y * w3.y + mv.z * w3.z + mv.w * w3.w;
      }
      size_t base = LOGIT_OFF + ((size_t)t * BB + b2) * OO + st * 128 + oo;
      out[base] = a0; out[base + 1] = a1; out[base + 2] = a2; out[base + 3] = a3;
    }
    __syncthreads();
  }
  {
    const float* lrow = &out[LOGIT_OFF + ((size_t)t * BB + b) * OO];
    float mx = -3.0e38f;
    for (int o = s8; o < OO; o += 8) mx = fmaxf(mx, lrow[o]);
    #pragma unroll
    for (int off = 4; off; off >>= 1) mx = fmaxf(mx, __shfl_xor(mx, off, 8));
    float zs = 0.f;
    for (int o = s8; o < OO; o += 8) zs += __expf(lrow[o] - mx);
    #pragma unroll
    for (int off = 4; off; off >>= 1) zs += __shfl_xor(zs, off, 8);
    float zi = 1.0f / zs;
    float* prow = &out[PRED_OFF + ((size_t)t * BB + b) * OO];
    for (int o = s8; o < OO; o += 8) prow[o] = __expf(lrow[o] - mx) * zi;
  }
}

// ---------------- launcher -------------------------------------------------------------
extern "C" void kernel_launch(void* const* d_in, const int* in_sizes, int n_in,
                              void* d_out, int out_size, void* d_ws, size_t ws_size,
                              hipStream_t stream) {
  (void)in_sizes; (void)n_in; (void)out_size; (void)ws_size;
  const int*   obs   = (const int*)d_in[0];
  const float* vel   = (const float*)d_in[1];
  const float* expl  = (const float*)d_in[2];
  const float* hinit = (const float*)d_in[3];
  const float* embW  = (const float*)d_in[4];
  const float* velW  = (const float*)d_in[5];
  const float* velb  = (const float*)d_in[6];
  const float* hW1   = (const float*)d_in[7];
  const float* hb1   = (const float*)d_in[8];
  const float* hW2   = (const float*)d_in[9];
  const float* hb2   = (const float*)d_in[10];
  const float* gW    = (const float*)d_in[11];
  const float* gb    = (const float*)d_in[12];
  const float* pW    = (const float*)d_in[13];
  const float* pb    = (const float*)d_in[14];
  const float* mW1   = (const float*)d_in[15];
  const float* mb1   = (const float*)d_in[16];
  const float* mW2   = (const float*)d_in[17];
  const float* mb2   = (const float*)d_in[18];
  const float* Wqk   = (const float*)d_in[19];
  const float* Wv    = (const float*)d_in[20];
  float* out = (float*)d_out;
  char* ws = (char*)d_ws;

  unsigned char*  w2p    = (unsigned char*)(ws + 0);            // 540,672 B
  unsigned char*  gwp    = (unsigned char*)(ws + 589824);       // 32,768 B
  float*          qbuf   = (float*)(ws + 1048576);              // 8 MB
  unsigned short* keysBF = (unsigned short*)(ws + 9437184);     // 4 MB
  unsigned short* valsBF = (unsigned short*)(ws + 13631488);    // 8 MB
  float*          Sg     = (float*)(ws + 22020096);             // 16 MB
  float*          probs  = (float*)(ws + 38797312);             // 128 KB

  k_pack  <<<dim3(560),  dim3(256), 0,                   stream>>>(hW2, hb2, gW, w2p, gwp);
  k_scan3 <<<dim3(16),   dim3(512), sizeof(Scan3Smem),   stream>>>(obs, vel, hinit, embW, velW, velb,
                                                                   hW1, hb1, gb, w2p, gwp, out);
  k_qkv   <<<dim3(256),  dim3(256), sizeof(QkvSmem),     stream>>>(out, Wqk, Wv, qbuf, keysBF, valsBF);
  k_scores<<<dim3(256),  dim3(128), sizeof(ScoresSmem),  stream>>>(qbuf, keysBF, expl, mW1, mb1, mW2, mb2,
                                                                   Sg, probs);
  k_attn  <<<dim3(1024), dim3(256), sizeof(AttnSmem),    stream>>>(Sg, probs, valsBF, pW, pb, out);
}